// Round 10
// baseline (331.908 us; speedup 1.0000x reference)
//
#include <hip/hip_runtime.h>

// B=8, C=256, N=2048, fp32 in/out.
// attn_b = (Ap_b x_b + cvec_b 1^T) / S
//   Ap_b = T1_b W3 + wvsx_b (x) u2 + bv (x) v2_b      (f16 hi/lo split MFMA)
//   T1_b = Wv G_b,  W3 = Wq^T Wk,  G_b = x_b x_b^T (symmetric)
//   u2 = Wk^T bq, w1 = Wq^T bk, s1 = bq.bk, sx_b = rowsum(x_b)
//   v2_b = W3^T sx_b + N u2;  s2_b = sx.w1 + N s1;  S = sum_b [v2.sx + N s2]
//   cvec_b = T1.w1 + wvsx*s1 + bv*s2
// SINGLE regular kernel (round-8 retry: LDS was undersized 40960<55808 -> OOB,
// that -- not the barrier -- caused the failure). 256 blocks x 256 threads,
// manual device-scope grid barrier (all 256 blocks co-resident on 256 CUs).
//   S1: gemmG splitK=8 (+rowsum) | W3 | u2/w1/s1     (209 busy)
//   S2: t1 (fold 8 Gpart slices) | prep2 | wvsx      (144 busy)
//   S3: ap + cvec                                    (128 busy)
//   S4: gemmF (in-kernel x transpose-convert)        (256 busy)

typedef _Float16 half8 __attribute__((ext_vector_type(8)));
typedef _Float16 half4 __attribute__((ext_vector_type(4)));
typedef _Float16 half2v __attribute__((ext_vector_type(2)));
typedef float f4v __attribute__((ext_vector_type(4)));

#define GP  40   // LDS pitch (halves), A panels / gemmG
#define GPB 36   // gemmF B panel pitch (18-dword rows: free 2-way banking)
#define NBLK 256

// generation-based grid barrier; bar[0]=counter, bar[1]=generation (memset to 0)
__device__ __forceinline__ void gbar(unsigned* bar) {
    __syncthreads();
    if (threadIdx.x == 0) {
        __threadfence();                                   // release prior writes (agent)
        const unsigned g = __hip_atomic_load(&bar[1], __ATOMIC_RELAXED, __HIP_MEMORY_SCOPE_AGENT);
        const unsigned a = __hip_atomic_fetch_add(&bar[0], 1u, __ATOMIC_ACQ_REL, __HIP_MEMORY_SCOPE_AGENT);
        if (a == NBLK - 1u) {
            __hip_atomic_store(&bar[0], 0u, __ATOMIC_RELAXED, __HIP_MEMORY_SCOPE_AGENT);
            __hip_atomic_store(&bar[1], g + 1u, __ATOMIC_RELEASE, __HIP_MEMORY_SCOPE_AGENT);
        } else {
            while (__hip_atomic_load(&bar[1], __ATOMIC_ACQUIRE, __HIP_MEMORY_SCOPE_AGENT) == g)
                __builtin_amdgcn_s_sleep(2);
        }
        __threadfence();                                   // acquire others' writes (agent)
    }
    __syncthreads();
}

__launch_bounds__(256, 1)
__global__ void mega_kernel(const float* __restrict__ x, const float* __restrict__ Wq,
                            const float* __restrict__ bq, const float* __restrict__ Wk,
                            const float* __restrict__ bk, const float* __restrict__ Wv,
                            const float* __restrict__ bv, float* __restrict__ out,
                            float* __restrict__ T1, float* __restrict__ W3,
                            float* __restrict__ sxpart, float* __restrict__ wvsx,
                            float* __restrict__ v2, float* __restrict__ cvec,
                            float* __restrict__ s2, float* __restrict__ u2,
                            float* __restrict__ w1, float* __restrict__ s1,
                            float* __restrict__ S, float* __restrict__ Gpart,
                            _Float16* __restrict__ Aph, _Float16* __restrict__ Apl,
                            unsigned* __restrict__ bar) {
    // stage-4 needs the most: Ah/Al 2*10240 + Bh/Bl 2*9216 + xt 16896 = 55808 B
    __shared__ __align__(16) char smem[55808];
    const int blk = blockIdx.x, t = threadIdx.x;
    const int lane = t & 63, wave = t >> 6;
    const int wy = wave >> 1, wx = wave & 1;
    const int mIn = lane & 15, quad = lane >> 4;

    // ================= S1: gemmG (0..191) | W3 (192..207) | vecs (208) =================
    if (blk < 192) {
        _Float16* Ah = (_Float16*)smem;
        _Float16* Al = Ah + 128 * GP;
        _Float16* Bh = Al + 128 * GP;
        _Float16* Bl = Bh + 128 * GP;
        const int tileId = blk % 3;
        const int y = blk / 3;                 // 0..63
        const int b = y >> 3, ks = y & 7;
        const int r0 = (tileId == 2) ? 128 : 0;
        const int c0 = (tileId == 0) ? 0 : 128;
        const bool diag = (tileId != 1);
        const float* xb = x + (long)b * 524288;

        f4v acc[4][4] = {};
        const int aBase = (wy * 64 + mIn) * GP + quad * 8;
        const int bBase = (wx * 64 + mIn) * GP + quad * 8;
        const int srow = t >> 3;               // 0..31
        const int skq  = (t & 7) * 4;          // 0..28
        float rs[4] = {};

        float4 pa[4], pb[4];
        int kk = ks * 256;
        #pragma unroll
        for (int i = 0; i < 4; ++i) {
            pa[i] = *(const float4*)&xb[(long)(r0 + srow + i * 32) * 2048 + kk + skq];
            if (!diag) pb[i] = *(const float4*)&xb[(long)(c0 + srow + i * 32) * 2048 + kk + skq];
        }

        for (int kb = 0; kb < 8; ++kb) {
            if (kb) __syncthreads();
            #pragma unroll
            for (int i = 0; i < 4; ++i) {
                const int row = srow + i * 32;
                half4 hv, lv;
                hv[0] = (_Float16)pa[i].x; lv[0] = (_Float16)(pa[i].x - (float)hv[0]);
                hv[1] = (_Float16)pa[i].y; lv[1] = (_Float16)(pa[i].y - (float)hv[1]);
                hv[2] = (_Float16)pa[i].z; lv[2] = (_Float16)(pa[i].z - (float)hv[2]);
                hv[3] = (_Float16)pa[i].w; lv[3] = (_Float16)(pa[i].w - (float)hv[3]);
                *(half4*)&Ah[row * GP + skq] = hv;
                *(half4*)&Al[row * GP + skq] = lv;
                if (diag) {
                    rs[i] += pa[i].x + pa[i].y + pa[i].z + pa[i].w;
                } else {
                    half4 hb, lb;
                    hb[0] = (_Float16)pb[i].x; lb[0] = (_Float16)(pb[i].x - (float)hb[0]);
                    hb[1] = (_Float16)pb[i].y; lb[1] = (_Float16)(pb[i].y - (float)hb[1]);
                    hb[2] = (_Float16)pb[i].z; lb[2] = (_Float16)(pb[i].z - (float)hb[2]);
                    hb[3] = (_Float16)pb[i].w; lb[3] = (_Float16)(pb[i].w - (float)hb[3]);
                    *(half4*)&Bh[row * GP + skq] = hb;
                    *(half4*)&Bl[row * GP + skq] = lb;
                }
            }
            __syncthreads();
            kk += 32;
            if (kb < 7) {
                #pragma unroll
                for (int i = 0; i < 4; ++i) {
                    pa[i] = *(const float4*)&xb[(long)(r0 + srow + i * 32) * 2048 + kk + skq];
                    if (!diag) pb[i] = *(const float4*)&xb[(long)(c0 + srow + i * 32) * 2048 + kk + skq];
                }
            }
            const _Float16* BhP = diag ? Ah : Bh;
            const _Float16* BlP = diag ? Al : Bl;
            #pragma unroll
            for (int ph = 0; ph < 3; ++ph) {
                const _Float16* As = (ph == 2) ? Al : Ah;
                const _Float16* Bs = (ph == 1) ? BlP : BhP;
                half8 af[4], bf[4];
                #pragma unroll
                for (int i = 0; i < 4; ++i) {
                    af[i] = *(const half8*)&As[aBase + i * 16 * GP];
                    bf[i] = *(const half8*)&Bs[bBase + i * 16 * GP];
                }
                #pragma unroll
                for (int i = 0; i < 4; ++i)
                    #pragma unroll
                    for (int j = 0; j < 4; ++j)
                        acc[i][j] = __builtin_amdgcn_mfma_f32_16x16x32_f16(af[i], bf[j], acc[i][j], 0, 0, 0);
            }
        }

        if (diag) {
            #pragma unroll
            for (int i = 0; i < 4; ++i) {
                rs[i] += __shfl_xor(rs[i], 1);
                rs[i] += __shfl_xor(rs[i], 2);
                rs[i] += __shfl_xor(rs[i], 4);
            }
            if ((t & 7) == 0) {
                #pragma unroll
                for (int i = 0; i < 4; ++i)
                    sxpart[ks * 2048 + b * 256 + r0 + srow + i * 32] = rs[i];
            }
        }

        float* D = Gpart + ((long)(ks * 8 + b) << 16);
        #pragma unroll
        for (int i = 0; i < 4; ++i)
            #pragma unroll
            for (int j = 0; j < 4; ++j) {
                const int row = r0 + wy * 64 + i * 16 + quad * 4;
                const int col = c0 + wx * 64 + j * 16 + mIn;
                #pragma unroll
                for (int r = 0; r < 4; ++r)
                    D[(row + r) * 256 + col] = acc[i][j][r];
                if (tileId == 1)
                    *(float4*)&D[(long)col * 256 + row] =
                        make_float4(acc[i][j][0], acc[i][j][1], acc[i][j][2], acc[i][j][3]);
            }
    } else if (blk < 208) {
        float* ldsA = (float*)smem;
        float* ldsB = ldsA + 16 * 68;
        const int tile = blk - 192;
        const int r0 = (tile >> 2) * 64, j0 = (tile & 3) * 64;
        const int tx = t & 15, ty = t >> 4;
        float acc[4][4] = {};
        for (int kk = 0; kk < 256; kk += 16) {
            *(float4*)&ldsA[ty * 68 + tx * 4] = *(const float4*)&Wq[(long)(kk + ty) * 256 + r0 + tx * 4];
            *(float4*)&ldsB[ty * 68 + tx * 4] = *(const float4*)&Wk[(long)(kk + ty) * 256 + j0 + tx * 4];
            __syncthreads();
            #pragma unroll
            for (int k = 0; k < 16; ++k) {
                const float4 av4 = *(const float4*)&ldsA[k * 68 + ty * 4];
                const float4 bv4 = *(const float4*)&ldsB[k * 68 + tx * 4];
                const float ar[4] = {av4.x, av4.y, av4.z, av4.w};
                const float br[4] = {bv4.x, bv4.y, bv4.z, bv4.w};
                #pragma unroll
                for (int i = 0; i < 4; ++i)
                    #pragma unroll
                    for (int j = 0; j < 4; ++j)
                        acc[i][j] = fmaf(ar[i], br[j], acc[i][j]);
            }
            __syncthreads();
        }
        #pragma unroll
        for (int i = 0; i < 4; ++i)
            *(float4*)&W3[(long)(r0 + ty * 4 + i) * 256 + j0 + tx * 4] =
                make_float4(acc[i][0], acc[i][1], acc[i][2], acc[i][3]);
    } else if (blk == 208) {
        float* sbq = (float*)smem;
        float* sbk = sbq + 256;
        float* red = sbk + 256;
        if (t == 0) S[0] = 0.0f;
        sbq[t] = bq[t]; sbk[t] = bk[t];
        __syncthreads();
        float u = 0.0f, w = 0.0f;
        #pragma unroll 8
        for (int c = 0; c < 256; ++c) {
            u = fmaf(Wk[(long)c * 256 + t], sbq[c], u);
            w = fmaf(Wq[(long)c * 256 + t], sbk[c], w);
        }
        u2[t] = u; w1[t] = w;
        red[t] = sbq[t] * sbk[t]; __syncthreads();
        for (int h = 128; h > 0; h >>= 1) { if (t < h) red[t] += red[t + h]; __syncthreads(); }
        if (t == 0) s1[0] = red[0];
    }

    gbar(bar);

    // ================= S2: t1 (0..127) | prep2 (128..135) | wvsx (136..143) =================
    if (blk < 128) {
        float* ldsA = (float*)smem;
        float* ldsB = ldsA + 16 * 68;
        const int j0 = (blk & 3) * 64;
        const int r0 = ((blk >> 2) & 3) * 64;
        const int b = blk >> 4;
        const int tx = t & 15, ty = t >> 4;
        const int sr = t >> 2, sk = (t & 3) * 4;
        float acc[4][4] = {};
        for (int kk = 0; kk < 256; kk += 16) {
            const float4 a4 = *(const float4*)&Wv[(long)(r0 + sr) * 256 + kk + sk];
            ldsA[(sk + 0) * 68 + sr] = a4.x;
            ldsA[(sk + 1) * 68 + sr] = a4.y;
            ldsA[(sk + 2) * 68 + sr] = a4.z;
            ldsA[(sk + 3) * 68 + sr] = a4.w;
            float4 bs = make_float4(0.f, 0.f, 0.f, 0.f);
            #pragma unroll
            for (int ksl = 0; ksl < 8; ++ksl) {
                const float4 g = *(const float4*)&Gpart[(long)ksl * 524288 + (long)b * 65536 +
                                                        (long)(kk + ty) * 256 + j0 + tx * 4];
                bs.x += g.x; bs.y += g.y; bs.z += g.z; bs.w += g.w;
            }
            *(float4*)&ldsB[ty * 68 + tx * 4] = bs;
            __syncthreads();
            #pragma unroll
            for (int k = 0; k < 16; ++k) {
                const float4 av4 = *(const float4*)&ldsA[k * 68 + ty * 4];
                const float4 bv4 = *(const float4*)&ldsB[k * 68 + tx * 4];
                const float ar[4] = {av4.x, av4.y, av4.z, av4.w};
                const float br[4] = {bv4.x, bv4.y, bv4.z, bv4.w};
                #pragma unroll
                for (int i = 0; i < 4; ++i)
                    #pragma unroll
                    for (int j = 0; j < 4; ++j)
                        acc[i][j] = fmaf(ar[i], br[j], acc[i][j]);
            }
            __syncthreads();
        }
        float* D = T1 + (long)b * 65536;
        #pragma unroll
        for (int i = 0; i < 4; ++i)
            *(float4*)&D[(long)(r0 + ty * 4 + i) * 256 + j0 + tx * 4] =
                make_float4(acc[i][0], acc[i][1], acc[i][2], acc[i][3]);
    } else if (blk < 136) {
        float* ssx = (float*)smem;
        float* red = ssx + 256;
        const int b = blk - 128, j = t;
        float sxv = 0.0f;
        #pragma unroll
        for (int ks = 0; ks < 8; ++ks) sxv += sxpart[ks * 2048 + b * 256 + j];
        ssx[j] = sxv;
        __syncthreads();
        float vr = 0.0f;
        #pragma unroll 8
        for (int c = 0; c < 256; ++c) vr = fmaf(W3[(long)c * 256 + j], ssx[c], vr);
        const float v2j = vr + 2048.0f * u2[j];
        v2[b * 256 + j] = v2j;
        red[j] = v2j * sxv; __syncthreads();
        for (int h = 128; h > 0; h >>= 1) { if (j < h) red[j] += red[j + h]; __syncthreads(); }
        const float sd1 = red[0];
        __syncthreads();
        red[j] = sxv * w1[j]; __syncthreads();
        for (int h = 128; h > 0; h >>= 1) { if (j < h) red[j] += red[j + h]; __syncthreads(); }
        if (j == 0) {
            const float s2v = red[0] + 2048.0f * s1[0];
            s2[b] = s2v;
            atomicAdd(S, sd1 + 2048.0f * s2v);
        }
    } else if (blk < 144) {
        float* wtile = (float*)smem;           // 32 x 256
        float* sxs = wtile + 8192;             // 2048
        const int r0w = (blk - 136) * 32;
        #pragma unroll
        for (int p = 0; p < 8; ++p) {
            const int f = t + p * 256;
            const int row = f >> 6, c4 = f & 63;
            *(float4*)&wtile[row * 256 + c4 * 4] = *(const float4*)&Wv[(long)(r0w + row) * 256 + c4 * 4];
        }
        #pragma unroll
        for (int p = 0; p < 8; ++p) {
            const int f = t + p * 256;
            float s = 0.0f;
            #pragma unroll
            for (int ks = 0; ks < 8; ++ks) s += sxpart[ks * 2048 + f];
            sxs[f] = s;
        }
        __syncthreads();
        const int r = t >> 3, q = t & 7;
        float acc[8] = {};
        for (int ci = 0; ci < 32; ++ci) {
            const float wv = wtile[r * 256 + q * 32 + ci];
            #pragma unroll
            for (int b = 0; b < 8; ++b) acc[b] = fmaf(wv, sxs[b * 256 + q * 32 + ci], acc[b]);
        }
        #pragma unroll
        for (int b = 0; b < 8; ++b) {
            acc[b] += __shfl_xor(acc[b], 1);
            acc[b] += __shfl_xor(acc[b], 2);
            acc[b] += __shfl_xor(acc[b], 4);
        }
        if (q == 0) {
            #pragma unroll
            for (int b = 0; b < 8; ++b) wvsx[b * 256 + r0w + r] = acc[b];
        }
    }

    gbar(bar);

    // ================= S3: ap (0..127) =================
    if (blk < 128) {
        float* ldsA = (float*)smem;
        float* ldsB = ldsA + 16 * 68;
        float* sw1 = ldsB + 16 * 68;
        const int b = blk >> 4;
        const int r0 = ((blk >> 2) & 3) * 64, j0 = (blk & 3) * 64;
        const float* A = T1 + (long)b * 65536;
        const int tx = t & 15, ty = t >> 4;
        const int sr = t >> 2, sk = (t & 3) * 4;
        sw1[t] = w1[t];
        float acc[4][4] = {};
        float dot[4] = {};
        for (int kk = 0; kk < 256; kk += 16) {
            const float4 a4 = *(const float4*)&A[(long)(r0 + sr) * 256 + kk + sk];
            ldsA[(sk + 0) * 68 + sr] = a4.x;
            ldsA[(sk + 1) * 68 + sr] = a4.y;
            ldsA[(sk + 2) * 68 + sr] = a4.z;
            ldsA[(sk + 3) * 68 + sr] = a4.w;
            *(float4*)&ldsB[ty * 68 + tx * 4] = *(const float4*)&W3[(long)(kk + ty) * 256 + j0 + tx * 4];
            __syncthreads();
            #pragma unroll
            for (int k = 0; k < 16; ++k) {
                const float4 av4 = *(const float4*)&ldsA[k * 68 + ty * 4];
                const float4 bv4 = *(const float4*)&ldsB[k * 68 + tx * 4];
                const float ar[4] = {av4.x, av4.y, av4.z, av4.w};
                const float br[4] = {bv4.x, bv4.y, bv4.z, bv4.w};
                const float wk = sw1[kk + k];
                #pragma unroll
                for (int i = 0; i < 4; ++i) {
                    dot[i] = fmaf(ar[i], wk, dot[i]);
                    #pragma unroll
                    for (int j = 0; j < 4; ++j)
                        acc[i][j] = fmaf(ar[i], br[j], acc[i][j]);
                }
            }
            __syncthreads();
        }
        #pragma unroll
        for (int i = 0; i < 4; ++i) {
            const int r = r0 + ty * 4 + i;
            const float e1 = wvsx[b * 256 + r], e3 = bv[r];
            half4 hv, lv;
            #pragma unroll
            for (int j = 0; j < 4; ++j) {
                const int col = j0 + tx * 4 + j;
                const float val = acc[i][j] + e1 * u2[col] + e3 * v2[b * 256 + col];
                hv[j] = (_Float16)val;
                lv[j] = (_Float16)(val - (float)hv[j]);
            }
            const long o = (long)b * 65536 + (long)r * 256 + j0 + tx * 4;
            *(half4*)&Aph[o] = hv;
            *(half4*)&Apl[o] = lv;
            if (j0 == 0 && tx == 0)
                cvec[b * 256 + r] = dot[i] + e1 * s1[0] + e3 * s2[b];
        }
    }

    gbar(bar);

    // ================= S4: gemmF (all 256) =================
    {
        _Float16* Ah = (_Float16*)smem;                       // 10240 B
        _Float16* Al = Ah + 128 * GP;                         // 10240 B
        _Float16* Bh = Al + 128 * GP;                         // 9216 B
        _Float16* Bl = Bh + 128 * GPB;                        // 9216 B
        float* xt = (float*)(Bl + 128 * GPB);                 // 16896 B -> total 55808
        const int n0 = (blk & 15) * 128;
        const int c0 = ((blk >> 4) & 1) * 128;
        const int b = blk >> 5;
        const _Float16* Asrc_h = Aph + (long)b * 65536;
        const _Float16* Asrc_l = Apl + (long)b * 65536;
        const float* xb = x + (long)b * 524288;

        f4v acc[4][4] = {};
        const int aBase = (wy * 64 + mIn) * GP + quad * 8;
        const int bBase = (wx * 64 + mIn) * GPB + quad * 8;
        const int cn = t & 127;
        const int ckh = (t >> 7) * 16;

        for (int kk = 0; kk < 256; kk += 32) {
            #pragma unroll
            for (int i = 0; i < 2; ++i) {
                const int idx = t + (i << 8);
                const int row = idx >> 2, ko = (idx & 3) << 3;
                *(uint4*)&Ah[row * GP + ko] = *(const uint4*)&Asrc_h[(long)(c0 + row) * 256 + kk + ko];
                *(uint4*)&Al[row * GP + ko] = *(const uint4*)&Asrc_l[(long)(c0 + row) * 256 + kk + ko];
            }
            #pragma unroll
            for (int p = 0; p < 4; ++p) {
                const int f = t + p * 256;
                const int k = f >> 5, n4 = f & 31;
                *(float4*)&xt[k * 132 + n4 * 4] = *(const float4*)&xb[(long)(kk + k) * 2048 + n0 + n4 * 4];
            }
            __syncthreads();
            {
                _Float16 hs[16], ls[16];
                #pragma unroll
                for (int k = 0; k < 16; ++k) {
                    const float v = xt[(ckh + k) * 132 + cn];
                    hs[k] = (_Float16)v;
                    ls[k] = (_Float16)(v - (float)hs[k]);
                }
                #pragma unroll
                for (int k2 = 0; k2 < 8; ++k2) {
                    half2v h2; h2[0] = hs[2 * k2]; h2[1] = hs[2 * k2 + 1];
                    half2v l2; l2[0] = ls[2 * k2]; l2[1] = ls[2 * k2 + 1];
                    *(half2v*)&Bh[cn * GPB + ckh + 2 * k2] = h2;
                    *(half2v*)&Bl[cn * GPB + ckh + 2 * k2] = l2;
                }
            }
            __syncthreads();
            #pragma unroll
            for (int ph = 0; ph < 3; ++ph) {
                const _Float16* As = (ph == 2) ? Al : Ah;
                const _Float16* Bs = (ph == 1) ? Bl : Bh;
                half8 af[4], bf[4];
                #pragma unroll
                for (int i = 0; i < 4; ++i) {
                    af[i] = *(const half8*)&As[aBase + i * 16 * GP];
                    const half4 b0 = *(const half4*)&Bs[bBase + i * 16 * GPB];
                    const half4 b1 = *(const half4*)&Bs[bBase + i * 16 * GPB + 4];
                    bf[i] = __builtin_shufflevector(b0, b1, 0, 1, 2, 3, 4, 5, 6, 7);
                }
                #pragma unroll
                for (int i = 0; i < 4; ++i)
                    #pragma unroll
                    for (int j = 0; j < 4; ++j)
                        acc[i][j] = __builtin_amdgcn_mfma_f32_16x16x32_f16(af[i], bf[j], acc[i][j], 0, 0, 0);
            }
            __syncthreads();
        }

        const float invS = 1.0f / S[0];
        float* ob = out + (long)b * 524288;
        const float* cv = cvec + b * 256;
        #pragma unroll
        for (int i = 0; i < 4; ++i)
            #pragma unroll
            for (int r = 0; r < 4; ++r) {
                const int row = c0 + wy * 64 + i * 16 + quad * 4 + r;
                const float c = cv[row];
                #pragma unroll
                for (int j = 0; j < 4; ++j) {
                    const int col = n0 + wx * 64 + j * 16 + mIn;
                    ob[(long)row * 2048 + col] = (acc[i][j][r] + c) * invS;
                }
            }
    }
}

extern "C" void kernel_launch(void* const* d_in, const int* in_sizes, int n_in,
                              void* d_out, int out_size, void* d_ws, size_t ws_size,
                              hipStream_t stream) {
    const float* x  = (const float*)d_in[0];
    const float* Wq = (const float*)d_in[1];
    const float* bq = (const float*)d_in[2];
    const float* Wk = (const float*)d_in[3];
    const float* bk = (const float*)d_in[4];
    const float* Wv = (const float*)d_in[5];
    const float* bv = (const float*)d_in[6];
    float* out = (float*)d_out;
    float* ws  = (float*)d_ws;

    float* T1     = ws;                  // 524288
    float* W3     = ws + 524288;         // 65536
    float* sxpart = ws + 589824;         // 8*2048
    float* wvsx   = ws + 606208;         // 2048
    float* v2     = ws + 608256;         // 2048
    float* cvec   = ws + 610304;         // 2048
    float* s2     = ws + 612352;         // 8
    float* u2     = ws + 612360;         // 256
    float* w1     = ws + 612616;         // 256
    float* s1     = ws + 612872;         // 1
    float* S      = ws + 612873;         // 1
    unsigned* bar = (unsigned*)(ws + 612874);    // 2 u32, memset below
    float* Gpart  = ws + 612880;         // 8*8*65536 = 4194304 (16 MB)
    _Float16* Aph = (_Float16*)(ws + 4807184);   // 524288 halves
    _Float16* Apl = Aph + 524288;                // total ws ~21 MB

    hipMemsetAsync(bar, 0, 2 * sizeof(unsigned), stream);
    mega_kernel<<<dim3(NBLK), 256, 0, stream>>>(x, Wq, bq, Wk, bk, Wv, bv, out,
                                                T1, W3, sxpart, wvsx, v2, cvec,
                                                s2, u2, w1, s1, S, Gpart, Aph, Apl, bar);
}

// Round 11
// 150.910 us; speedup vs baseline: 2.1994x; 2.1994x over previous
//
#include <hip/hip_runtime.h>

// B=8, C=256, N=2048, fp32 in/out.
// attn_b = (Ap_b x_b + cvec_b 1^T) / S
//   Ap_b = T1_b W3 + wvsx_b (x) u2 + bv (x) v2_b      (f16 hi/lo split MFMA)
//   T1_b = Wv G_b,  W3 = Wq^T Wk,  G_b = x_b x_b^T (symmetric)
//   u2 = Wk^T bq, w1 = Wq^T bk, s1 = bq.bk, sx_b = rowsum(x_b)
//   v2_b = W3^T sx_b + N u2;  s2_b = sx.w1 + N s1;  S = sum_b [v2.sx + N s2]
//   cvec_b = T1.w1 + wvsx*s1 + bv*s2    (computed inside ap)
// 4 serial nodes (round-9 structure; fused mega-kernel REGRESSED 2.2x: agent-scope
// acquire spin invalidates L2 per poll + <=50% stage utilization).
// New in this round: XCD-aware block swizzles in k1 (3 tiles of one (b,ks) share
// an XCD -> x L2 reuse) and k2 (4 r0-blocks sharing a (b,j0) Gpart panel share
// an XCD -> Gpart L2 reuse).

typedef _Float16 half8 __attribute__((ext_vector_type(8)));
typedef _Float16 half4 __attribute__((ext_vector_type(4)));
typedef _Float16 half2v __attribute__((ext_vector_type(2)));
typedef float f4v __attribute__((ext_vector_type(4)));

#define GP  40   // LDS pitch (halves), A panels / gemmG (16B-aligned rows)
#define GPB 36   // gemmF B panel pitch: 18-dword row stride -> 2-way (free) banking

// ---------------- K1: gemmG splitK=8 (+rowsum) | W3 | u2/w1/s1 ----------------
// blocks 0..191: gemmG; 192..207: W3 tiles; 208: u2/w1/s1 + zero S.
__launch_bounds__(256)
__global__ void k1_kernel(const float* __restrict__ x, const float* __restrict__ Wq,
                          const float* __restrict__ Wk, const float* __restrict__ bq,
                          const float* __restrict__ bk, float* __restrict__ sxpart,
                          float* __restrict__ W3, float* __restrict__ u2,
                          float* __restrict__ w1, float* __restrict__ s1,
                          float* __restrict__ S, float* __restrict__ Gpart) {
    __shared__ __align__(16) char smem[40960];
    const int blk = blockIdx.x, t = threadIdx.x;
    if (blk < 192) {
        _Float16* Ah = (_Float16*)smem;
        _Float16* Al = Ah + 128 * GP;
        _Float16* Bh = Al + 128 * GP;
        _Float16* Bl = Bh + 128 * GP;
        // XCD swizzle: tiles 0..2 of the same y are 64 apart -> identical blk%8
        // -> same XCD -> shared x rows hit that XCD's L2 instead of HBM twice.
        const int tileId = blk >> 6;           // 0..2
        const int y = blk & 63;                // 0..63
        const int b = y >> 3, ks = y & 7;
        const int r0 = (tileId == 2) ? 128 : 0;
        const int c0 = (tileId == 0) ? 0 : 128;
        const bool diag = (tileId != 1);
        const float* xb = x + (long)b * 524288;

        const int lane = t & 63, wave = t >> 6;
        const int wy = wave >> 1, wx = wave & 1;
        const int mIn = lane & 15, quad = lane >> 4;

        f4v acc[4][4] = {};
        const int aBase = (wy * 64 + mIn) * GP + quad * 8;
        const int bBase = (wx * 64 + mIn) * GP + quad * 8;
        const int srow = t >> 3;               // 0..31
        const int skq  = (t & 7) * 4;          // 0..28
        float rs[4] = {};                      // rowsum partials (diag only)

        float4 pa[4], pb[4];
        int kk = ks * 256;
        #pragma unroll
        for (int i = 0; i < 4; ++i) {
            pa[i] = *(const float4*)&xb[(long)(r0 + srow + i * 32) * 2048 + kk + skq];
            if (!diag) pb[i] = *(const float4*)&xb[(long)(c0 + srow + i * 32) * 2048 + kk + skq];
        }

        for (int kb = 0; kb < 8; ++kb) {
            if (kb) __syncthreads();
            #pragma unroll
            for (int i = 0; i < 4; ++i) {
                const int row = srow + i * 32;
                half4 hv, lv;
                hv[0] = (_Float16)pa[i].x; lv[0] = (_Float16)(pa[i].x - (float)hv[0]);
                hv[1] = (_Float16)pa[i].y; lv[1] = (_Float16)(pa[i].y - (float)hv[1]);
                hv[2] = (_Float16)pa[i].z; lv[2] = (_Float16)(pa[i].z - (float)hv[2]);
                hv[3] = (_Float16)pa[i].w; lv[3] = (_Float16)(pa[i].w - (float)hv[3]);
                *(half4*)&Ah[row * GP + skq] = hv;
                *(half4*)&Al[row * GP + skq] = lv;
                if (diag) {
                    rs[i] += pa[i].x + pa[i].y + pa[i].z + pa[i].w;
                } else {
                    half4 hb, lb;
                    hb[0] = (_Float16)pb[i].x; lb[0] = (_Float16)(pb[i].x - (float)hb[0]);
                    hb[1] = (_Float16)pb[i].y; lb[1] = (_Float16)(pb[i].y - (float)hb[1]);
                    hb[2] = (_Float16)pb[i].z; lb[2] = (_Float16)(pb[i].z - (float)hb[2]);
                    hb[3] = (_Float16)pb[i].w; lb[3] = (_Float16)(pb[i].w - (float)hb[3]);
                    *(half4*)&Bh[row * GP + skq] = hb;
                    *(half4*)&Bl[row * GP + skq] = lb;
                }
            }
            __syncthreads();
            kk += 32;
            if (kb < 7) {
                #pragma unroll
                for (int i = 0; i < 4; ++i) {
                    pa[i] = *(const float4*)&xb[(long)(r0 + srow + i * 32) * 2048 + kk + skq];
                    if (!diag) pb[i] = *(const float4*)&xb[(long)(c0 + srow + i * 32) * 2048 + kk + skq];
                }
            }
            const _Float16* BhP = diag ? Ah : Bh;
            const _Float16* BlP = diag ? Al : Bl;
            #pragma unroll
            for (int ph = 0; ph < 3; ++ph) {
                const _Float16* As = (ph == 2) ? Al : Ah;
                const _Float16* Bs = (ph == 1) ? BlP : BhP;
                half8 af[4], bf[4];
                #pragma unroll
                for (int i = 0; i < 4; ++i) {
                    af[i] = *(const half8*)&As[aBase + i * 16 * GP];
                    bf[i] = *(const half8*)&Bs[bBase + i * 16 * GP];
                }
                #pragma unroll
                for (int i = 0; i < 4; ++i)
                    #pragma unroll
                    for (int j = 0; j < 4; ++j)
                        acc[i][j] = __builtin_amdgcn_mfma_f32_16x16x32_f16(af[i], bf[j], acc[i][j], 0, 0, 0);
            }
        }

        if (diag) {
            #pragma unroll
            for (int i = 0; i < 4; ++i) {
                rs[i] += __shfl_xor(rs[i], 1);
                rs[i] += __shfl_xor(rs[i], 2);
                rs[i] += __shfl_xor(rs[i], 4);
            }
            if ((t & 7) == 0) {
                #pragma unroll
                for (int i = 0; i < 4; ++i)
                    sxpart[ks * 2048 + b * 256 + r0 + srow + i * 32] = rs[i];
            }
        }

        float* D = Gpart + ((long)(ks * 8 + b) << 16);
        #pragma unroll
        for (int i = 0; i < 4; ++i)
            #pragma unroll
            for (int j = 0; j < 4; ++j) {
                const int row = r0 + wy * 64 + i * 16 + quad * 4;
                const int col = c0 + wx * 64 + j * 16 + mIn;
                #pragma unroll
                for (int r = 0; r < 4; ++r)
                    D[(row + r) * 256 + col] = acc[i][j][r];
                if (tileId == 1)
                    *(float4*)&D[(long)col * 256 + row] =
                        make_float4(acc[i][j][0], acc[i][j][1], acc[i][j][2], acc[i][j][3]);
            }
    } else if (blk < 208) {
        float* ldsA = (float*)smem;
        float* ldsB = ldsA + 16 * 68;
        const int tile = blk - 192;
        const int r0 = (tile >> 2) * 64, j0 = (tile & 3) * 64;
        const int tx = t & 15, ty = t >> 4;
        float acc[4][4] = {};
        for (int kk = 0; kk < 256; kk += 16) {
            *(float4*)&ldsA[ty * 68 + tx * 4] = *(const float4*)&Wq[(long)(kk + ty) * 256 + r0 + tx * 4];
            *(float4*)&ldsB[ty * 68 + tx * 4] = *(const float4*)&Wk[(long)(kk + ty) * 256 + j0 + tx * 4];
            __syncthreads();
            #pragma unroll
            for (int k = 0; k < 16; ++k) {
                const float4 av4 = *(const float4*)&ldsA[k * 68 + ty * 4];
                const float4 bv4 = *(const float4*)&ldsB[k * 68 + tx * 4];
                const float ar[4] = {av4.x, av4.y, av4.z, av4.w};
                const float br[4] = {bv4.x, bv4.y, bv4.z, bv4.w};
                #pragma unroll
                for (int i = 0; i < 4; ++i)
                    #pragma unroll
                    for (int j = 0; j < 4; ++j)
                        acc[i][j] = fmaf(ar[i], br[j], acc[i][j]);
            }
            __syncthreads();
        }
        #pragma unroll
        for (int i = 0; i < 4; ++i)
            *(float4*)&W3[(long)(r0 + ty * 4 + i) * 256 + j0 + tx * 4] =
                make_float4(acc[i][0], acc[i][1], acc[i][2], acc[i][3]);
    } else {
        float* sbq = (float*)smem;
        float* sbk = sbq + 256;
        float* red = sbk + 256;
        if (t == 0) S[0] = 0.0f;
        sbq[t] = bq[t]; sbk[t] = bk[t];
        __syncthreads();
        float u = 0.0f, w = 0.0f;
        #pragma unroll 8
        for (int c = 0; c < 256; ++c) {
            u = fmaf(Wk[(long)c * 256 + t], sbq[c], u);   // coalesced columns
            w = fmaf(Wq[(long)c * 256 + t], sbk[c], w);
        }
        u2[t] = u; w1[t] = w;
        red[t] = sbq[t] * sbk[t]; __syncthreads();
        for (int h = 128; h > 0; h >>= 1) { if (t < h) red[t] += red[t + h]; __syncthreads(); }
        if (t == 0) s1[0] = red[0];
    }
}

// ---------------- K2: t1 (0..127) | prep2 (128..135) | wvsx (136..143) ----------------
__launch_bounds__(256)
__global__ void k2_kernel(const float* __restrict__ Wv, const float* __restrict__ Gpart,
                          const float* __restrict__ W3, const float* __restrict__ u2,
                          const float* __restrict__ w1, const float* __restrict__ s1p,
                          const float* __restrict__ sxpart, float* __restrict__ T1,
                          float* __restrict__ v2, float* __restrict__ s2,
                          float* __restrict__ wvsx, float* __restrict__ S) {
    __shared__ __align__(16) char smem[40960];
    const int blk = blockIdx.x, t = threadIdx.x;
    if (blk < 128) {
        float* ldsA = (float*)smem;
        float* ldsB = ldsA + 16 * 68;
        // XCD swizzle: the 4 r0-blocks sharing one (b,j0) Gpart B-panel are 32
        // apart -> identical blk%8 -> same XCD -> panel read hits L2 3 of 4 times.
        const int r0 = (blk >> 5) * 64;        // 0..3
        const int g  = blk & 31;
        const int b  = g >> 2;
        const int j0 = (g & 3) * 64;
        const int tx = t & 15, ty = t >> 4;
        const int sr = t >> 2, sk = (t & 3) * 4;
        float acc[4][4] = {};
        for (int kk = 0; kk < 256; kk += 16) {
            const float4 a4 = *(const float4*)&Wv[(long)(r0 + sr) * 256 + kk + sk];
            ldsA[(sk + 0) * 68 + sr] = a4.x;
            ldsA[(sk + 1) * 68 + sr] = a4.y;
            ldsA[(sk + 2) * 68 + sr] = a4.z;
            ldsA[(sk + 3) * 68 + sr] = a4.w;
            float4 bs = make_float4(0.f, 0.f, 0.f, 0.f);
            #pragma unroll
            for (int ksl = 0; ksl < 8; ++ksl) {         // fold splitK reduce into staging
                const float4 g4 = *(const float4*)&Gpart[(long)ksl * 524288 + (long)b * 65536 +
                                                         (long)(kk + ty) * 256 + j0 + tx * 4];
                bs.x += g4.x; bs.y += g4.y; bs.z += g4.z; bs.w += g4.w;
            }
            *(float4*)&ldsB[ty * 68 + tx * 4] = bs;
            __syncthreads();
            #pragma unroll
            for (int k = 0; k < 16; ++k) {
                const float4 av4 = *(const float4*)&ldsA[k * 68 + ty * 4];
                const float4 bv4 = *(const float4*)&ldsB[k * 68 + tx * 4];
                const float ar[4] = {av4.x, av4.y, av4.z, av4.w};
                const float br[4] = {bv4.x, bv4.y, bv4.z, bv4.w};
                #pragma unroll
                for (int i = 0; i < 4; ++i)
                    #pragma unroll
                    for (int j = 0; j < 4; ++j)
                        acc[i][j] = fmaf(ar[i], br[j], acc[i][j]);
            }
            __syncthreads();
        }
        float* D = T1 + (long)b * 65536;
        #pragma unroll
        for (int i = 0; i < 4; ++i)
            *(float4*)&D[(long)(r0 + ty * 4 + i) * 256 + j0 + tx * 4] =
                make_float4(acc[i][0], acc[i][1], acc[i][2], acc[i][3]);
    } else if (blk < 136) {
        float* ssx = (float*)smem;
        float* red = ssx + 256;
        const int b = blk - 128, j = t;
        float sxv = 0.0f;
        #pragma unroll
        for (int ks = 0; ks < 8; ++ks) sxv += sxpart[ks * 2048 + b * 256 + j];
        ssx[j] = sxv;
        __syncthreads();
        float vr = 0.0f;
        #pragma unroll 8
        for (int c = 0; c < 256; ++c) vr = fmaf(W3[(long)c * 256 + j], ssx[c], vr); // coalesced
        const float v2j = vr + 2048.0f * u2[j];
        v2[b * 256 + j] = v2j;
        red[j] = v2j * sxv; __syncthreads();
        for (int h = 128; h > 0; h >>= 1) { if (j < h) red[j] += red[j + h]; __syncthreads(); }
        const float sd1 = red[0];
        __syncthreads();
        red[j] = sxv * w1[j]; __syncthreads();
        for (int h = 128; h > 0; h >>= 1) { if (j < h) red[j] += red[j + h]; __syncthreads(); }
        if (j == 0) {
            const float s2v = red[0] + 2048.0f * s1p[0];
            s2[b] = s2v;
            atomicAdd(S, sd1 + 2048.0f * s2v);
        }
    } else {
        float* wtile = (float*)smem;           // 32 x 256
        float* sxs = wtile + 8192;             // 2048
        const int r0w = (blk - 136) * 32;
        #pragma unroll
        for (int p = 0; p < 8; ++p) {
            const int f = t + p * 256;
            const int row = f >> 6, c4 = f & 63;
            *(float4*)&wtile[row * 256 + c4 * 4] = *(const float4*)&Wv[(long)(r0w + row) * 256 + c4 * 4];
        }
        #pragma unroll
        for (int p = 0; p < 8; ++p) {
            const int f = t + p * 256;
            float s = 0.0f;
            #pragma unroll
            for (int ks = 0; ks < 8; ++ks) s += sxpart[ks * 2048 + f];
            sxs[f] = s;
        }
        __syncthreads();
        const int r = t >> 3, q = t & 7;       // 32 rows x 8 k-groups
        float acc[8] = {};
        for (int ci = 0; ci < 32; ++ci) {
            const float wv = wtile[r * 256 + q * 32 + ci];
            #pragma unroll
            for (int b = 0; b < 8; ++b) acc[b] = fmaf(wv, sxs[b * 256 + q * 32 + ci], acc[b]);
        }
        #pragma unroll
        for (int b = 0; b < 8; ++b) {
            acc[b] += __shfl_xor(acc[b], 1);
            acc[b] += __shfl_xor(acc[b], 2);
            acc[b] += __shfl_xor(acc[b], 4);
        }
        if (q == 0) {
            #pragma unroll
            for (int b = 0; b < 8; ++b) wvsx[b * 256 + r0w + r] = acc[b];
        }
    }
}

// ---------------- K3: Ap = T1 W3 + wvsx(x)u2 + bv(x)v2 -> f16 hi/lo; cvec fold ----------------
__launch_bounds__(256)
__global__ void ap_kernel(const float* __restrict__ T1, const float* __restrict__ W3,
                          const float* __restrict__ wvsx, const float* __restrict__ u2,
                          const float* __restrict__ bv, const float* __restrict__ v2,
                          const float* __restrict__ w1, const float* __restrict__ s1p,
                          const float* __restrict__ s2, _Float16* __restrict__ Aph,
                          _Float16* __restrict__ Apl, float* __restrict__ cvec) {
    __shared__ float ldsA[16 * 68], ldsB[16 * 68], sw1[256];
    const int b = blockIdx.z;
    const int r0 = blockIdx.y * 64, j0 = blockIdx.x * 64;
    const float* A = T1 + (long)b * 65536;
    const int t = threadIdx.x, tx = t & 15, ty = t >> 4;
    const int sr = t >> 2, sk = (t & 3) * 4;
    sw1[t] = w1[t];
    float acc[4][4] = {};
    float dot[4] = {};
    for (int kk = 0; kk < 256; kk += 16) {
        const float4 a4 = *(const float4*)&A[(long)(r0 + sr) * 256 + kk + sk];
        ldsA[(sk + 0) * 68 + sr] = a4.x;
        ldsA[(sk + 1) * 68 + sr] = a4.y;
        ldsA[(sk + 2) * 68 + sr] = a4.z;
        ldsA[(sk + 3) * 68 + sr] = a4.w;
        *(float4*)&ldsB[ty * 68 + tx * 4] = *(const float4*)&W3[(long)(kk + ty) * 256 + j0 + tx * 4];
        __syncthreads();
        #pragma unroll
        for (int k = 0; k < 16; ++k) {
            const float4 av4 = *(const float4*)&ldsA[k * 68 + ty * 4];
            const float4 bv4 = *(const float4*)&ldsB[k * 68 + tx * 4];
            const float ar[4] = {av4.x, av4.y, av4.z, av4.w};
            const float br[4] = {bv4.x, bv4.y, bv4.z, bv4.w};
            const float wk = sw1[kk + k];
            #pragma unroll
            for (int i = 0; i < 4; ++i) {
                dot[i] = fmaf(ar[i], wk, dot[i]);
                #pragma unroll
                for (int j = 0; j < 4; ++j)
                    acc[i][j] = fmaf(ar[i], br[j], acc[i][j]);
            }
        }
        __syncthreads();
    }
    #pragma unroll
    for (int i = 0; i < 4; ++i) {
        const int r = r0 + ty * 4 + i;
        const float e1 = wvsx[b * 256 + r], e3 = bv[r];
        half4 hv, lv;
        #pragma unroll
        for (int j = 0; j < 4; ++j) {
            const int col = j0 + tx * 4 + j;
            const float val = acc[i][j] + e1 * u2[col] + e3 * v2[b * 256 + col];
            hv[j] = (_Float16)val;
            lv[j] = (_Float16)(val - (float)hv[j]);
        }
        const long o = (long)b * 65536 + (long)r * 256 + j0 + tx * 4;
        *(half4*)&Aph[o] = hv;
        *(half4*)&Apl[o] = lv;
        if (j0 == 0 && tx == 0)
            cvec[b * 256 + r] = dot[i] + e1 * s1p[0] + e3 * s2[b];
    }
}

// ---------------- K4: out = (Ap x + cvec 1^T) / S ; x converted in-kernel ----------------
__launch_bounds__(256)
__global__ void gemmF_mfma(const _Float16* __restrict__ Aph, const _Float16* __restrict__ Apl,
                           const float* __restrict__ x, const float* __restrict__ Sptr,
                           const float* __restrict__ cvec, float* __restrict__ out) {
    __shared__ __align__(16) _Float16 Ah[128 * GP];
    __shared__ __align__(16) _Float16 Al[128 * GP];
    __shared__ __align__(16) _Float16 Bh[128 * GPB];
    __shared__ __align__(16) _Float16 Bl[128 * GPB];
    __shared__ __align__(16) float xt[32 * 132];

    const int n0 = blockIdx.x * 128;
    const int c0 = blockIdx.y * 128;
    const int b = blockIdx.z;
    const _Float16* Asrc_h = Aph + (long)b * 65536;
    const _Float16* Asrc_l = Apl + (long)b * 65536;
    const float* xb = x + (long)b * 524288;

    const int t = threadIdx.x;
    const int lane = t & 63, wave = t >> 6;
    const int wy = wave >> 1, wx = wave & 1;
    const int mIn = lane & 15, quad = lane >> 4;

    f4v acc[4][4] = {};
    const int aBase = (wy * 64 + mIn) * GP + quad * 8;
    const int bBase = (wx * 64 + mIn) * GPB + quad * 8;
    const int cn = t & 127;          // converter: n index
    const int ckh = (t >> 7) * 16;   // converter: k half-range

    for (int kk = 0; kk < 256; kk += 32) {
        #pragma unroll
        for (int i = 0; i < 2; ++i) {
            const int idx = t + (i << 8);
            const int row = idx >> 2, ko = (idx & 3) << 3;
            *(uint4*)&Ah[row * GP + ko] = *(const uint4*)&Asrc_h[(long)(c0 + row) * 256 + kk + ko];
            *(uint4*)&Al[row * GP + ko] = *(const uint4*)&Asrc_l[(long)(c0 + row) * 256 + kk + ko];
        }
        #pragma unroll
        for (int p = 0; p < 4; ++p) {
            const int f = t + p * 256;
            const int k = f >> 5, n4 = f & 31;
            *(float4*)&xt[k * 132 + n4 * 4] = *(const float4*)&xb[(long)(kk + k) * 2048 + n0 + n4 * 4];
        }
        __syncthreads();
        {
            _Float16 hs[16], ls[16];
            #pragma unroll
            for (int k = 0; k < 16; ++k) {
                const float v = xt[(ckh + k) * 132 + cn];      // 2-way LDS read (free)
                hs[k] = (_Float16)v;
                ls[k] = (_Float16)(v - (float)hs[k]);
            }
            #pragma unroll
            for (int k2 = 0; k2 < 8; ++k2) {
                half2v h2; h2[0] = hs[2 * k2]; h2[1] = hs[2 * k2 + 1];
                half2v l2; l2[0] = ls[2 * k2]; l2[1] = ls[2 * k2 + 1];
                *(half2v*)&Bh[cn * GPB + ckh + 2 * k2] = h2;   // 18-dword stride: 2-way (free)
                *(half2v*)&Bl[cn * GPB + ckh + 2 * k2] = l2;
            }
        }
        __syncthreads();
        #pragma unroll
        for (int ph = 0; ph < 3; ++ph) {
            const _Float16* As = (ph == 2) ? Al : Ah;
            const _Float16* Bs = (ph == 1) ? Bl : Bh;
            half8 af[4], bf[4];
            #pragma unroll
            for (int i = 0; i < 4; ++i) {
                af[i] = *(const half8*)&As[aBase + i * 16 * GP];
                const half4 b0 = *(const half4*)&Bs[bBase + i * 16 * GPB];
                const half4 b1 = *(const half4*)&Bs[bBase + i * 16 * GPB + 4];
                bf[i] = __builtin_shufflevector(b0, b1, 0, 1, 2, 3, 4, 5, 6, 7);
            }
            #pragma unroll
            for (int i = 0; i < 4; ++i)
                #pragma unroll
                for (int j = 0; j < 4; ++j)
                    acc[i][j] = __builtin_amdgcn_mfma_f32_16x16x32_f16(af[i], bf[j], acc[i][j], 0, 0, 0);
        }
        __syncthreads();
    }

    const float invS = 1.0f / Sptr[0];
    float* ob = out + (long)b * 524288;
    const float* cv = cvec + b * 256;
    #pragma unroll
    for (int i = 0; i < 4; ++i)
        #pragma unroll
        for (int r = 0; r < 4; ++r) {
            const int row = c0 + wy * 64 + i * 16 + quad * 4 + r;
            const float c = cv[row];
            #pragma unroll
            for (int j = 0; j < 4; ++j) {
                const int col = n0 + wx * 64 + j * 16 + mIn;
                ob[(long)row * 2048 + col] = (acc[i][j][r] + c) * invS;
            }
        }
}

extern "C" void kernel_launch(void* const* d_in, const int* in_sizes, int n_in,
                              void* d_out, int out_size, void* d_ws, size_t ws_size,
                              hipStream_t stream) {
    const float* x  = (const float*)d_in[0];
    const float* Wq = (const float*)d_in[1];
    const float* bq = (const float*)d_in[2];
    const float* Wk = (const float*)d_in[3];
    const float* bk = (const float*)d_in[4];
    const float* Wv = (const float*)d_in[5];
    const float* bv = (const float*)d_in[6];
    float* out = (float*)d_out;
    float* ws  = (float*)d_ws;

    float* T1     = ws;                  // 524288
    float* W3     = ws + 524288;         // 65536
    float* sxpart = ws + 589824;         // 8*2048
    float* wvsx   = ws + 606208;         // 2048
    float* v2     = ws + 608256;         // 2048
    float* cvec   = ws + 610304;         // 2048
    float* s2     = ws + 612352;         // 8
    float* u2     = ws + 612360;         // 256
    float* w1     = ws + 612616;         // 256
    float* s1     = ws + 612872;         // 1
    float* S      = ws + 612873;         // 1
    float* Gpart  = ws + 612880;         // 8*8*65536 = 4194304 (16 MB)
    _Float16* Aph = (_Float16*)(ws + 4807184);   // 524288 halves
    _Float16* Apl = Aph + 524288;                // total ws ~21 MB

    k1_kernel<<<dim3(209), 256, 0, stream>>>(x, Wq, Wk, bq, bk, sxpart, W3, u2, w1, s1, S, Gpart);
    k2_kernel<<<dim3(144), 256, 0, stream>>>(Wv, Gpart, W3, u2, w1, s1, sxpart, T1, v2, s2, wvsx, S);
    ap_kernel<<<dim3(4, 4, 8), 256, 0, stream>>>(T1, W3, wvsx, u2, bv, v2, w1, s1, s2, Aph, Apl, cvec);
    gemmF_mfma<<<dim3(16, 2, 8), 256, 0, stream>>>(Aph, Apl, x, S, cvec, out);
}